// Round 9
// baseline (214.048 us; speedup 1.0000x reference)
//
#include <hip/hip_runtime.h>
#include <hip/hip_bf16.h>
#include <cmath>

// Problem constants
#define BATCH   64
#define NPG     1024           // nodes per graph
#define NODES   65536          // BATCH*NPG
#define EDGES   524288
#define FIN     14
#define NH      128
#define KP1     820
#define KP2     656

typedef __attribute__((ext_vector_type(8))) short bf16x8;
typedef __attribute__((ext_vector_type(4))) float f32x4;

static __device__ __forceinline__ unsigned short f2bf(float f) {
  __hip_bfloat16 h = __float2bfloat16(f);
  return *reinterpret_cast<unsigned short*>(&h);
}

// ---------------------------------------------------------------------------
// init: zero cnt (64 blocks) + build bf16 W2 fragment table (16 blocks).
// Wfrag[(c*8+sg)*64+lane] = 8 bf16 of out-row c*16+(lane&15),
// k=(sg&3)*32+(lane>>4)*8; sg<4 from W2rel else W2root. 64KB, L2-hot.
// ---------------------------------------------------------------------------
__global__ __launch_bounds__(256) void k_init(
    int4* __restrict__ cnt4, const float* __restrict__ W2rel,
    const float* __restrict__ W2rt, unsigned short* __restrict__ Wfrag) {
  int b = blockIdx.x;
  if (b < 64) {
    cnt4[b * 256 + threadIdx.x] = make_int4(0, 0, 0, 0);
    return;
  }
  int id = (b - 64) * 256 + threadIdx.x;      // 4096 total
  int lane = id & 63, sg = (id >> 6) & 7, c = id >> 9;
  const float* SW = (sg < 4) ? W2rel : W2rt;
  int o = c * 16 + (lane & 15);
  int k = (sg & 3) * 32 + (lane >> 4) * 8;
  float4 f0 = *(const float4*)(SW + (size_t)o * NH + k);
  float4 f1 = *(const float4*)(SW + (size_t)o * NH + k + 4);
  union { unsigned short us[8]; uint4 v; } p;
  p.us[0] = f2bf(f0.x); p.us[1] = f2bf(f0.y);
  p.us[2] = f2bf(f0.z); p.us[3] = f2bf(f0.w);
  p.us[4] = f2bf(f1.x); p.us[5] = f2bf(f1.y);
  p.us[6] = f2bf(f1.z); p.us[7] = f2bf(f1.w);
  *(uint4*)(Wfrag + (size_t)id * 8) = p.v;
}

// ---------------------------------------------------------------------------
// CSR build (by dst): histogram -> 2-level exclusive scan -> fill
// ---------------------------------------------------------------------------
__global__ __launch_bounds__(256) void k_hist(
    const int* __restrict__ dst, int* __restrict__ cnt) {
  int e = blockIdx.x * 256 + threadIdx.x;
  atomicAdd(&cnt[dst[e]], 1);
}

__global__ __launch_bounds__(256) void k_scan_local(
    const int* __restrict__ cnt, int* __restrict__ rowptr,
    int* __restrict__ bsum) {
  __shared__ int s[256];
  int t = threadIdx.x, b = blockIdx.x;
  int v = cnt[b * 256 + t];
  s[t] = v;
  __syncthreads();
  for (int d = 1; d < 256; d <<= 1) {
    int add = (t >= d) ? s[t - d] : 0;
    __syncthreads();
    s[t] += add;
    __syncthreads();
  }
  rowptr[b * 256 + t] = s[t] - v;      // exclusive, block-local
  if (t == 255) bsum[b] = s[255];
}

// merged base-scan + final: each block redundantly scans bsum[256] in LDS
__global__ __launch_bounds__(256) void k_scan_final(
    int* __restrict__ rowptr, const int* __restrict__ bsum,
    int* __restrict__ cursor) {
  __shared__ int s[256];
  int t = threadIdx.x, b = blockIdx.x;
  int v = bsum[t];
  s[t] = v;
  __syncthreads();
  for (int d = 1; d < 256; d <<= 1) {
    int add = (t >= d) ? s[t - d] : 0;
    __syncthreads();
    s[t] += add;
    __syncthreads();
  }
  int base = (b == 0) ? 0 : s[b - 1];    // exclusive prefix of block b
  int id = b * 256 + t;
  int v2 = rowptr[id] + base;
  rowptr[id] = v2;
  cursor[id] = v2;
  if (id == 0) rowptr[NODES] = EDGES;
}

__global__ __launch_bounds__(256) void k_fill(
    const int* __restrict__ src, const int* __restrict__ dst,
    int* __restrict__ cursor, int* __restrict__ col) {
  int e = blockIdx.x * 256 + threadIdx.x;
  int pos = atomicAdd(&cursor[dst[e]], 1);
  col[pos] = src[e];
}

// ---------------------------------------------------------------------------
// conv1 aggregation via CSR gather (XCD-swizzled for per-graph L2 locality)
// ---------------------------------------------------------------------------
__global__ __launch_bounds__(256) void k_gather1(
    const float* __restrict__ x, const int* __restrict__ rowptr,
    const int* __restrict__ col, float* __restrict__ agg1) {
  int bid = blockIdx.x;                       // 4096 blocks, 512 per XCD chunk
  int swz = (bid & 7) * 512 + (bid >> 3);
  int t = threadIdx.x;
  int gi = t >> 4, l = t & 15;
  int n = swz * 16 + gi;
  int rs = rowptr[n], re = rowptr[n + 1];
  if (l < FIN) {
    float acc = 0.f;
    for (int j = rs; j < re; ++j) {
      int v = col[j];
      acc += x[(size_t)v * FIN + l];
    }
    agg1[(size_t)n * FIN + l] = acc;
  }
}

// ---------------------------------------------------------------------------
// conv1 GEMM + relu + fused pool1 score (norm computed inline via shfl).
// Block 256 thr / 64 nodes; thread = 4 nodes x 8 outs (cols og*4+j, 64+og*4+j)
// ---------------------------------------------------------------------------
__global__ __launch_bounds__(256) void k_gemm1(
    const float* __restrict__ x, const float* __restrict__ agg1,
    const float* __restrict__ Wrel, const float* __restrict__ brel,
    const float* __restrict__ Wroot, const float* __restrict__ p1w,
    float* __restrict__ h1, float* __restrict__ s1) {
  __shared__ float As[64 * FIN];
  __shared__ float Xs[64 * FIN];
  __shared__ float Wl[2 * FIN][NH];
  int t = threadIdx.x;
  int nb = blockIdx.x * 64;
  for (int i = t; i < 64 * FIN; i += 256) {
    As[i] = agg1[(size_t)nb * FIN + i];
    Xs[i] = x[(size_t)nb * FIN + i];
  }
  for (int i = t; i < NH * FIN; i += 256) {
    int o = i / FIN, k = i - o * FIN;
    Wl[k][o]       = Wrel[i];
    Wl[k + FIN][o] = Wroot[i];
  }
  __syncthreads();
  int og = t & 15, ng = t >> 4, ra = ng * 4;
  float bb[8], pw[8];
#pragma unroll
  for (int j = 0; j < 4; ++j) {
    int c0 = og * 4 + j, c1 = 64 + og * 4 + j;
    bb[j] = brel[c0]; bb[j + 4] = brel[c1];
    pw[j] = p1w[c0];  pw[j + 4] = p1w[c1];
  }
  // rn1 = 1/||p1w||: 16-lane og-group covers all 128 cols
  float q = 0.f;
#pragma unroll
  for (int j = 0; j < 8; ++j) q += pw[j] * pw[j];
  q += __shfl_xor(q, 1); q += __shfl_xor(q, 2);
  q += __shfl_xor(q, 4); q += __shfl_xor(q, 8);
  float rnorm = rsqrtf(q);

  float acc[4][8];
#pragma unroll
  for (int i = 0; i < 4; ++i)
#pragma unroll
    for (int j = 0; j < 8; ++j) acc[i][j] = bb[j];
#pragma unroll
  for (int k = 0; k < FIN; ++k) {
    float4 w0 = *(const float4*)&Wl[k][og * 4];
    float4 w1 = *(const float4*)&Wl[k][64 + og * 4];
#pragma unroll
    for (int i = 0; i < 4; ++i) {
      float a = As[(ra + i) * FIN + k];
      acc[i][0] += a * w0.x; acc[i][1] += a * w0.y;
      acc[i][2] += a * w0.z; acc[i][3] += a * w0.w;
      acc[i][4] += a * w1.x; acc[i][5] += a * w1.y;
      acc[i][6] += a * w1.z; acc[i][7] += a * w1.w;
    }
  }
#pragma unroll
  for (int k = 0; k < FIN; ++k) {
    float4 w0 = *(const float4*)&Wl[FIN + k][og * 4];
    float4 w1 = *(const float4*)&Wl[FIN + k][64 + og * 4];
#pragma unroll
    for (int i = 0; i < 4; ++i) {
      float a = Xs[(ra + i) * FIN + k];
      acc[i][0] += a * w0.x; acc[i][1] += a * w0.y;
      acc[i][2] += a * w0.z; acc[i][3] += a * w0.w;
      acc[i][4] += a * w1.x; acc[i][5] += a * w1.y;
      acc[i][6] += a * w1.z; acc[i][7] += a * w1.w;
    }
  }
#pragma unroll
  for (int i = 0; i < 4; ++i) {
    int n = nb + ra + i;
    float pv = 0.f;
#pragma unroll
    for (int j = 0; j < 8; ++j) {
      float v = fmaxf(acc[i][j], 0.f);
      acc[i][j] = v;
      pv += v * pw[j];
    }
    *(float4*)(h1 + (size_t)n * NH + og * 4) =
        make_float4(acc[i][0], acc[i][1], acc[i][2], acc[i][3]);
    *(float4*)(h1 + (size_t)n * NH + 64 + og * 4) =
        make_float4(acc[i][4], acc[i][5], acc[i][6], acc[i][7]);
    pv += __shfl_xor(pv, 1);
    pv += __shfl_xor(pv, 2);
    pv += __shfl_xor(pv, 4);
    pv += __shfl_xor(pv, 8);
    if (og == 0) s1[n] = tanhf(pv * rnorm);
  }
}

// ---------------------------------------------------------------------------
// exact per-graph top-K: 512 threads, bitonic over 1024 keys.
// Stages with j<=64 are wave-local (each wave owns a 128-elem LDS segment:
// for t in [64w,64w+64), i=((t&~(j-1))<<1)|(t&(j-1)) lies in [128w,128w+128))
// -> no __syncthreads needed; compile-time memory fence pins LDS ordering.
// Barriers only for j>=128 stages + one per k-block: 55 -> ~16 barriers.
// ---------------------------------------------------------------------------
__global__ __launch_bounds__(512) void k_topk(
    const float* __restrict__ score, const int* __restrict__ mask_in,
    int* __restrict__ kept, int K) {
  __shared__ unsigned long long keys[1024];
  int t = threadIdx.x, g = blockIdx.x;
  for (int i = t; i < 1024; i += 512) {
    int n = g * NPG + i;
    unsigned int inv;
    if (mask_in && !mask_in[n]) {
      inv = 0xFFFFFFFFu;
    } else {
      unsigned int u   = __float_as_uint(score[n]);
      unsigned int ord = (u & 0x80000000u) ? ~u : (u | 0x80000000u);
      inv = ~ord;
    }
    keys[i] = ((unsigned long long)inv << 32) | (unsigned int)i;
  }
  __syncthreads();
  for (int k = 2; k <= 1024; k <<= 1) {
    int j = k >> 1;
    for (; j >= 128; j >>= 1) {            // cross-wave stages
      int i = ((t & ~(j - 1)) << 1) | (t & (j - 1));
      int p = i | j;
      unsigned long long a = keys[i], b = keys[p];
      bool up = ((i & k) == 0);
      if ((a > b) == up) { keys[i] = b; keys[p] = a; }
      __syncthreads();
    }
    for (; j > 0; j >>= 1) {               // wave-local stages
      int i = ((t & ~(j - 1)) << 1) | (t & (j - 1));
      int p = i | j;
      unsigned long long a = keys[i], b = keys[p];
      bool up = ((i & k) == 0);
      if ((a > b) == up) { keys[i] = b; keys[p] = a; }
      asm volatile("" ::: "memory");       // no-reorder fence, zero cost
    }
    __syncthreads();
  }
  for (int i = t; i < 1024; i += 512) {
    int idx = (int)(keys[i] & 0xFFFFFFFFu);
    kept[g * NPG + idx] = (i < K) ? 1 : 0;
  }
}

// ---------------------------------------------------------------------------
// readout partials over kept nodes: v = h[n]*s[n]  (read-only).
// If s1m != null, also writes s1m[n] = kept[n] ? s[n] : 0 (for k_conv2).
// ---------------------------------------------------------------------------
__global__ __launch_bounds__(256) void k_readout(
    const float* __restrict__ h, const float* __restrict__ s,
    const int* __restrict__ kept, float* __restrict__ psum,
    float* __restrict__ pmax, float* __restrict__ s1m) {
  int g = blockIdx.x >> 4, c = blockIdx.x & 15;
  int f = threadIdx.x & 127, half = threadIdx.x >> 7;
  int nbase = g * NPG + c * 64 + half;
  float sum = 0.f, mx = -1e30f;
  for (int i = 0; i < 64; i += 2) {
    int n = nbase + i;
    int kp = kept[n];
    if (s1m && f == 0) s1m[n] = kp ? s[n] : 0.f;
    if (kp) {
      float v = h[(size_t)n * NH + f] * s[n];
      sum += v;
      mx = fmaxf(mx, v);
    }
  }
  int slot = blockIdx.x * 2 + half;
  psum[(size_t)slot * NH + f] = sum;
  pmax[(size_t)slot * NH + f] = mx;
}

// ---------------------------------------------------------------------------
// FUSED conv2: CSR gather + bf16 MFMA GEMM + relu + pool2 score.
// Zero LDS, zero barriers. Per lane (row16=lane&15, kgrp=lane>>4):
//  - gather its own A-fragment K-slices in f32: ag[s][0..7] = sum over edges
//    s1m[v] * h1[v][kgrp*8 + s*32 ..], 4 independent 32B loads/edge;
//  - convert to bf16 a[0..3]; a[4..7] = own row h1*s1m (root term);
//  - 64 MFMAs streaming W fragments from the 64KB L2-hot Wfrag table.
// Dropped dst rows (kept1=0) skip the gather; their inputs are all-zero so
// outputs are finite; s2 masked by topk2's mask_in; h2 write gated.
// D layout: col=lane&15, row=(lane>>4)*4+reg (m89). XCD-swizzled.
// ---------------------------------------------------------------------------
__global__ __launch_bounds__(256) void k_conv2(
    const float* __restrict__ h1, const float* __restrict__ s1m,
    const int* __restrict__ rowptr, const int* __restrict__ col,
    const int* __restrict__ kept1, const unsigned short* __restrict__ Wfrag,
    const float* __restrict__ b2, const float* __restrict__ p2w,
    float* __restrict__ h2, float* __restrict__ s2) {
  int t = threadIdx.x;
  int bid = blockIdx.x;                 // 1024 blocks, 128 per XCD chunk
  int swz = (bid & 7) * 128 + (bid >> 3);
  int nb = swz * 64;
  int lane = t & 63, w = t >> 6;
  int row16 = lane & 15, kgrp = lane >> 4;
  int myrow = nb + 16 * w + row16;

  // ---- gather phase: per-lane f32 accumulation of A K-slices ----
  float ag[4][8];
#pragma unroll
  for (int s = 0; s < 4; ++s)
#pragma unroll
    for (int u = 0; u < 8; ++u) ag[s][u] = 0.f;
  if (kept1[myrow]) {
    int rs = rowptr[myrow], re = rowptr[myrow + 1];
    const float* hb = h1 + (size_t)kgrp * 8;
    for (int j = rs; j < re; ++j) {
      int v = col[j];
      float sv = s1m[v];
      if (sv != 0.f) {
        const float* hv = hb + (size_t)v * NH;
#pragma unroll
        for (int s = 0; s < 4; ++s) {
          float4 q0 = *(const float4*)(hv + s * 32);
          float4 q1 = *(const float4*)(hv + s * 32 + 4);
          ag[s][0] += sv * q0.x; ag[s][1] += sv * q0.y;
          ag[s][2] += sv * q0.z; ag[s][3] += sv * q0.w;
          ag[s][4] += sv * q1.x; ag[s][5] += sv * q1.y;
          ag[s][6] += sv * q1.z; ag[s][7] += sv * q1.w;
        }
      }
    }
  }

  // ---- build bf16 A fragments ----
  bf16x8 a[8];
#pragma unroll
  for (int s = 0; s < 4; ++s) {
    union { unsigned short us[8]; bf16x8 v; } p;
#pragma unroll
    for (int u = 0; u < 8; ++u) p.us[u] = f2bf(ag[s][u]);
    a[s] = p.v;
  }
  {
    float sc = s1m[myrow];
    const float* S = h1 + (size_t)myrow * NH;
#pragma unroll
    for (int s = 0; s < 4; ++s) {
      int k = s * 32 + kgrp * 8;
      float4 f0 = *(const float4*)(S + k);
      float4 f1 = *(const float4*)(S + k + 4);
      union { unsigned short us[8]; bf16x8 v; } p;
      p.us[0] = f2bf(f0.x * sc); p.us[1] = f2bf(f0.y * sc);
      p.us[2] = f2bf(f0.z * sc); p.us[3] = f2bf(f0.w * sc);
      p.us[4] = f2bf(f1.x * sc); p.us[5] = f2bf(f1.y * sc);
      p.us[6] = f2bf(f1.z * sc); p.us[7] = f2bf(f1.w * sc);
      a[4 + s] = p.v;
    }
  }

  // ---- MFMA: stream W fragments from L2 ----
  f32x4 acc[8];
#pragma unroll
  for (int c = 0; c < 8; ++c) acc[c] = (f32x4){0.f, 0.f, 0.f, 0.f};
  const bf16x8* WF = (const bf16x8*)Wfrag;
#pragma unroll
  for (int c = 0; c < 8; ++c) {
#pragma unroll
    for (int s = 0; s < 8; ++s) {
      bf16x8 wv = WF[(c * 8 + s) * 64 + lane];
      acc[c] = __builtin_amdgcn_mfma_f32_16x16x32_bf16(a[s], wv, acc[c], 0, 0, 0);
    }
  }

  // ---- epilogue: bias + relu + gated h2 write + fused pool2 score ----
  float bb[8], pw[8];
#pragma unroll
  for (int c = 0; c < 8; ++c) {
    bb[c] = b2[c * 16 + row16];
    pw[c] = p2w[c * 16 + row16];
  }
  float q2 = 0.f;
#pragma unroll
  for (int c = 0; c < 8; ++c) q2 += pw[c] * pw[c];
  q2 += __shfl_xor(q2, 1); q2 += __shfl_xor(q2, 2);
  q2 += __shfl_xor(q2, 4); q2 += __shfl_xor(q2, 8);
  float rnorm = rsqrtf(q2);

  int msr[4];
#pragma unroll
  for (int r = 0; r < 4; ++r) msr[r] = kept1[nb + 16 * w + kgrp * 4 + r];

  float pvp[4] = {0.f, 0.f, 0.f, 0.f};
#pragma unroll
  for (int c = 0; c < 8; ++c) {
#pragma unroll
    for (int r = 0; r < 4; ++r) {
      float u = fmaxf(acc[c][r] + bb[c], 0.f);
      pvp[r] += u * pw[c];
      if (msr[r]) {                      // kept2 subset of kept1 -> safe skip
        int n = nb + 16 * w + kgrp * 4 + r;
        h2[(size_t)n * NH + c * 16 + row16] = u;
      }
    }
  }
#pragma unroll
  for (int r = 0; r < 4; ++r) {
    float pv = pvp[r];
    pv += __shfl_xor(pv, 1);
    pv += __shfl_xor(pv, 2);
    pv += __shfl_xor(pv, 4);
    pv += __shfl_xor(pv, 8);
    if (row16 == 0) {
      int n = nb + 16 * w + kgrp * 4 + r;
      s2[n] = tanhf(pv * rnorm);
    }
  }
}

// ---------------------------------------------------------------------------
// final combine (32 partial slots per graph)
// ---------------------------------------------------------------------------
__global__ __launch_bounds__(256) void k_final(
    const float* __restrict__ psum1, const float* __restrict__ pmax1,
    const float* __restrict__ psum2, const float* __restrict__ pmax2,
    float* __restrict__ out) {
  int g = blockIdx.x, t = threadIdx.x;
  if (t < 128) {
    float a = 0.f, b = 0.f;
#pragma unroll
    for (int c = 0; c < 32; ++c) {
      a += psum1[(size_t)(g * 32 + c) * NH + t];
      b += psum2[(size_t)(g * 32 + c) * NH + t];
    }
    out[(size_t)g * 256 + t] = a / (float)KP1 + b / (float)KP2;
  } else {
    int f = t - 128;
    float a = -1e30f, b = -1e30f;
#pragma unroll
    for (int c = 0; c < 32; ++c) {
      a = fmaxf(a, pmax1[(size_t)(g * 32 + c) * NH + f]);
      b = fmaxf(b, pmax2[(size_t)(g * 32 + c) * NH + f]);
    }
    out[(size_t)g * 256 + t] = a + b;
  }
}

// ---------------------------------------------------------------------------
extern "C" void kernel_launch(void* const* d_in, const int* in_sizes, int n_in,
                              void* d_out, int out_size, void* d_ws, size_t ws_size,
                              hipStream_t stream) {
  const float* x     = (const float*)d_in[0];
  const int*   eidx  = (const int*)d_in[1];
  const int*   src   = eidx;
  const int*   dst   = eidx + EDGES;
  const float* W1rel = (const float*)d_in[3];
  const float* b1    = (const float*)d_in[4];
  const float* W1rt  = (const float*)d_in[5];
  const float* p1w   = (const float*)d_in[6];
  const float* W2rel = (const float*)d_in[7];
  const float* b2    = (const float*)d_in[8];
  const float* W2rt  = (const float*)d_in[9];
  const float* p2w   = (const float*)d_in[10];
  float* out = (float*)d_out;

  // workspace layout (floats)
  float* ws = (float*)d_ws;
  size_t off = 0;
  float* h1    = ws + off; off += (size_t)NODES * NH;
  float* h2    = ws + off; off += (size_t)NODES * NH;
  float* agg1  = ws + off; off += (size_t)NODES * FIN;
  float* s1    = ws + off; off += NODES;
  float* s2    = ws + off; off += NODES;
  float* s1m   = ws + off; off += NODES;
  int*   kept1 = (int*)(ws + off); off += NODES;
  int*   kept2 = (int*)(ws + off); off += NODES;
  float* psum1 = ws + off; off += 2048 * NH;
  float* pmax1 = ws + off; off += 2048 * NH;
  float* psum2 = ws + off; off += 2048 * NH;
  float* pmax2 = ws + off; off += 2048 * NH;
  unsigned short* Wfrag = (unsigned short*)(ws + off); off += 16384; // 64 KB
  int*   cnt     = (int*)(ws + off); off += NODES;
  int*   rowptr  = (int*)(ws + off); off += NODES + 1;
  int*   cursor  = (int*)(ws + off); off += NODES;
  int*   bsum    = (int*)(ws + off); off += 256;
  int*   col     = (int*)(ws + off); off += EDGES;

  // ---- init (zero cnt + W fragment prep) + CSR build ----
  k_init<<<80, 256, 0, stream>>>((int4*)cnt, W2rel, W2rt, Wfrag);
  k_hist<<<EDGES / 256, 256, 0, stream>>>(dst, cnt);
  k_scan_local<<<NODES / 256, 256, 0, stream>>>(cnt, rowptr, bsum);
  k_scan_final<<<NODES / 256, 256, 0, stream>>>(rowptr, bsum, cursor);
  k_fill<<<EDGES / 256, 256, 0, stream>>>(src, dst, cursor, col);

  // ---- layer 1 ----
  k_gather1<<<NODES / 16, 256, 0, stream>>>(x, rowptr, col, agg1);
  k_gemm1<<<NODES / 64, 256, 0, stream>>>(x, agg1, W1rel, b1, W1rt, p1w,
                                          h1, s1);
  k_topk<<<BATCH, 512, 0, stream>>>(s1, nullptr, kept1, KP1);
  k_readout<<<BATCH * 16, 256, 0, stream>>>(h1, s1, kept1, psum1, pmax1, s1m);

  // ---- layer 2 (fused gather + MFMA GEMM) ----
  k_conv2<<<NODES / 64, 256, 0, stream>>>(h1, s1m, rowptr, col, kept1, Wfrag,
                                          b2, p2w, h2, s2);
  k_topk<<<BATCH, 512, 0, stream>>>(s2, kept1, kept2, KP2);
  k_readout<<<BATCH * 16, 256, 0, stream>>>(h2, s2, kept2, psum2, pmax2,
                                            nullptr);
  k_final<<<BATCH, 256, 0, stream>>>(psum1, pmax1, psum2, pmax2, out);
}